// Round 2
// baseline (99.157 us; speedup 1.0000x reference)
//
#include <hip/hip_runtime.h>
#include <math.h>

// Problem constants (IMG=1024, B=2, A=20, levels i=2..6)
#define NANCH 261888          // anchors per batch = 3*(256^2+128^2+64^2+32^2+16^2)
#define NB 2
#define NGT 20

// Flat float32 output layout (concatenated in return order)
#define OFF_BOX   (2*NB*NANCH)                 // scores are [0, OFF_BOX)
#define OFF_ANC   (OFF_BOX + 4*NB*NANCH)
#define OFF_LAB   (OFF_ANC + 4*NB*NANCH)

__global__ __launch_bounds__(256) void rpn_fused2(
    const float* __restrict__ cs2, const float* __restrict__ bp2,
    const float* __restrict__ cs3, const float* __restrict__ bp3,
    const float* __restrict__ cs4, const float* __restrict__ bp4,
    const float* __restrict__ cs5, const float* __restrict__ bp5,
    const float* __restrict__ cs6, const float* __restrict__ bp6,
    const float* __restrict__ gt,  const int* __restrict__ cnt_raw,
    float* __restrict__ out)
{
    // Stage GT boxes (+precomputed area) and counts in LDS
    __shared__ float sgt[NB*NGT*5];
    __shared__ int scnt[NB];
    int tid = threadIdx.x;
    if (tid < NB*NGT) {
        float g0 = gt[tid*4+0], g1 = gt[tid*4+1], g2 = gt[tid*4+2], g3 = gt[tid*4+3];
        sgt[tid*5+0] = g0; sgt[tid*5+1] = g1;
        sgt[tid*5+2] = g2; sgt[tid*5+3] = g3;
        sgt[tid*5+4] = (g2 - g0) * (g3 - g1);    // ga, same fp order as reference
    }
    if (tid == 0) {
        // gt_counts is int64 in the reference; counts >=1 so hi-word==0 iff int64.
        int w0 = cnt_raw[0], w1 = cnt_raw[1];
        if (w1 == 0) { scnt[0] = w0; scnt[1] = cnt_raw[2]; }   // int64: [lo0,hi0,lo1,hi1]
        else         { scnt[0] = w0; scnt[1] = w1; }           // int32: [c0,c1]
    }
    __syncthreads();

    // Two consecutive anchors per thread. All level/type/row subblock sizes are
    // even, so the pair (n, n+1) always shares level, anchor type, and row y.
    int p = blockIdx.x * 256 + tid;            // pair index, [0, NB*NANCH/2)
    int t = p * 2;
    int b = (t >= NANCH) ? 1 : 0;
    int n = t - b*NANCH;                       // even

    const float* cs; const float* bp;
    int off, lhw, lw; float s, hs, aw;
    if (n < 196608)      { cs=cs2; bp=bp2; off=0;      lhw=16; lw=8; s=4.f;  hs=1.5f;  aw=64.f;  }
    else if (n < 245760) { cs=cs3; bp=bp3; off=196608; lhw=14; lw=7; s=8.f;  hs=3.5f;  aw=128.f; }
    else if (n < 258048) { cs=cs4; bp=bp4; off=245760; lhw=12; lw=6; s=16.f; hs=7.5f;  aw=256.f; }
    else if (n < 261120) { cs=cs5; bp=bp5; off=258048; lhw=10; lw=5; s=32.f; hs=15.5f; aw=512.f; }
    else                 { cs=cs6; bp=bp6; off=261120; lhw=8;  lw=4; s=64.f; hs=31.5f; aw=1024.f;}

    int local = n - off;                 // even
    int a   = local >> lhw;              // anchor type 0..2
    int rem = local & ((1 << lhw) - 1);  // y*w + x, even
    int y   = rem >> lw;
    int x   = rem & ((1 << lw) - 1);     // even; x+1 < w
    int hw  = 1 << lhw;

    // scores (channel permute): cs[b, a*2+c, y, x..x+1] — float2 loads (8B aligned)
    int cbase = ((b*6 + a*2) << lhw) + rem;
    float2 c0 = *(const float2*)(cs + cbase);
    float2 c1 = *(const float2*)(cs + cbase + hw);
    // deltas: bp[b, a*4+d, y, x..x+1]
    int dbase = ((b*12 + a*4) << lhw) + rem;
    float2 d0 = *(const float2*)(bp + dbase);
    float2 d1 = *(const float2*)(bp + dbase + hw);
    float2 d2 = *(const float2*)(bp + dbase + 2*hw);
    float2 d3 = *(const float2*)(bp + dbase + 3*hw);

    // anchors (exact in fp32)
    float cy  = s * (float)y + hs;
    float cxa = s * (float)x + hs;
    float cxb = s * (float)(x + 1) + hs;
    float hh = (a == 2) ? 2.f*aw : aw;
    float ww = (a == 0) ? 2.f*aw : aw;

    // apply deltas -> boxes (2% threshold; fma/expf fine here)
    float cyca = cy  + d0.x*hh,  cycb = cy  + d0.y*hh;
    float cxca = cxa + d1.x*ww,  cxcb = cxb + d1.y*ww;
    float h2a  = hh * expf(d2.x), h2b = hh * expf(d2.y);
    float w2a  = ww * expf(d3.x), w2b = ww * expf(d3.y);

    int gi = b*NANCH + n;                // even
    ((float4*)out)[gi >> 1] = make_float4(c0.x, c1.x, c0.y, c1.y);
    float4* boxp = (float4*)(out + OFF_BOX);
    boxp[gi]   = make_float4(cyca - 0.5f*h2a, cxca - 0.5f*w2a,
                             cyca + 0.5f*h2a, cxca + 0.5f*w2a);
    boxp[gi+1] = make_float4(cycb - 0.5f*h2b, cxcb - 0.5f*w2b,
                             cycb + 0.5f*h2b, cxcb + 0.5f*w2b);
    float4* ancp = (float4*)(out + OFF_ANC);
    ancp[gi]   = make_float4(cy, cxa, hh, ww);
    ancp[gi+1] = make_float4(cy, cxb, hh, ww);

    // labels — replicate reference fp32 op order exactly; forbid contraction so
    // (area+ga)-inter and the clip chain stay bit-identical to numpy.
    {
#pragma clang fp contract(off)
        float y1  = cy - hh*0.5f;
        float y2  = y1 + hh;
        float x1a = cxa - ww*0.5f, x2a = x1a + ww;
        float x1b = cxb - ww*0.5f, x2b = x1b + ww;
        float area = hh * ww;
        int cnt = scnt[b];
        const float* gp = &sgt[b*NGT*5];
        bool pa = false, pb = false;
        for (int g = 0; g < cnt; ++g) {
            float gy1 = gp[g*5+0], gx1 = gp[g*5+1];
            float gy2 = gp[g*5+2], gx2 = gp[g*5+3];
            float ga  = gp[g*5+4];
            // y-extent shared by the pair (same cy, hh)
            float yy1 = fminf(fmaxf(y1, gy1), gy2);
            float yy2 = fminf(fmaxf(y2, gy1), gy2);
            float dy  = yy2 - yy1;
            float apg = area + ga;
            // anchor A
            float xx1a = fminf(fmaxf(x1a, gx1), gx2);
            float xx2a = fminf(fmaxf(x2a, gx1), gx2);
            float intA = dy * (xx2a - xx1a);
            float uniA = apg - intA;
            pa = pa || (intA / uniA >= 0.5f);
            // anchor B
            float xx1b = fminf(fmaxf(x1b, gx1), gx2);
            float xx2b = fminf(fmaxf(x2b, gx1), gx2);
            float intB = dy * (xx2b - xx1b);
            float uniB = apg - intB;
            pb = pb || (intB / uniB >= 0.5f);
        }
        *(float2*)(out + OFF_LAB + gi) = make_float2(pa ? 1.0f : 0.0f,
                                                     pb ? 1.0f : 0.0f);
    }
}

extern "C" void kernel_launch(void* const* d_in, const int* in_sizes, int n_in,
                              void* d_out, int out_size, void* d_ws, size_t ws_size,
                              hipStream_t stream) {
    // setup_inputs() order: cs2,bp2,cs3,bp3,cs4,bp4,cs5,bp5,cs6,bp6,gt_bboxes,gt_counts,img_h,img_w
    const int pairs = NB * NANCH / 2;           // 261,888 -> exactly 1023 blocks of 256
    rpn_fused2<<<(pairs + 255) / 256, 256, 0, stream>>>(
        (const float*)d_in[0], (const float*)d_in[1],
        (const float*)d_in[2], (const float*)d_in[3],
        (const float*)d_in[4], (const float*)d_in[5],
        (const float*)d_in[6], (const float*)d_in[7],
        (const float*)d_in[8], (const float*)d_in[9],
        (const float*)d_in[10], (const int*)d_in[11],
        (float*)d_out);
}